// Round 11
// baseline (159.951 us; speedup 1.0000x reference)
//
#include <hip/hip_runtime.h>

#define B_ 8
#define T_ 2048
#define H_ 256
#define PSTR 40                  // P LDS row stride (elems): 32+8
#define SCALE2 0.0901684403f     // (1/16) * log2(e)
#define SLOPE2 0.00563552752f    // 2^-8 * log2(e)
#define ELEMS ((size_t)B_ * T_ * H_)

typedef __attribute__((ext_vector_type(8))) short bf16x8;
typedef __attribute__((ext_vector_type(4))) float f32x4;
typedef __attribute__((ext_vector_type(16))) float f32x16;

#define MFMA32(a, b, c) __builtin_amdgcn_mfma_f32_32x32x16_bf16((a), (b), (c), 0, 0, 0)

__device__ __forceinline__ ushort f2bf(float f) {
  unsigned u = __float_as_uint(f);
  u += 0x7FFFu + ((u >> 16) & 1u);   // RNE; finite inputs
  return (ushort)(u >> 16);
}

// async 16B/lane global->LDS DMA (contiguous: LDS = uniform base + lane*16)
__device__ __forceinline__ void gl_lds16(const ushort* g, ushort* l) {
  __builtin_amdgcn_global_load_lds(
      (const __attribute__((address_space(1))) unsigned int*)g,
      (__attribute__((address_space(3))) unsigned int*)l, 16, 0, 0);
}

// ---- prologue: blocks [0,1024) RoPE(k)->bf16 blocked ktile; [1024,2048) v transpose ----
// ktile layout: [b][it=t/32][d8=d/8][kv=t%32][8]   (16KB contiguous per (b,it) tile)
// vtile layout: [b][it][kvq=(t%32)/8][h][8]
__global__ void prep_kernel(const float* __restrict__ k, const float* __restrict__ v,
                            ushort* __restrict__ kt, ushort* __restrict__ vt) {
  __shared__ ushort tile[64][72];
  const int bid = blockIdx.x;
  const int tid = threadIdx.x;
  if (bid < 1024) {
    // K RoPE: thread = (bt, d8); reads 2x32B coalesced, writes 2x16B vector stores
    int idx = bid * 256 + tid;          // over B*T*16
    int d8 = idx & 15;
    int bt = idx >> 4;
    int t = bt & (T_ - 1);
    int b = bt >> 11;
    size_t base = (size_t)bt * H_ + d8 * 8;
    float4 a0 = *(const float4*)(k + base);
    float4 a1 = *(const float4*)(k + base + 4);
    float4 c0 = *(const float4*)(k + base + 128);
    float4 c1 = *(const float4*)(k + base + 132);
    float av[8] = {a0.x, a0.y, a0.z, a0.w, a1.x, a1.y, a1.z, a1.w};
    float cv[8] = {c0.x, c0.y, c0.z, c0.w, c1.x, c1.y, c1.z, c1.w};
    bf16x8 lo, hi;
#pragma unroll
    for (int e = 0; e < 8; ++e) {
      int j = d8 * 8 + e;
      float rv = (float)t * exp2f((float)j * -0.103810252959f) * 0.15915494309f;
      float fr = rv - floorf(rv);
      float sn = __builtin_amdgcn_sinf(fr), cs = __builtin_amdgcn_cosf(fr);
      lo[e] = (short)f2bf(av[e] * cs - cv[e] * sn);
      hi[e] = (short)f2bf(cv[e] * cs + av[e] * sn);
    }
    size_t kdst = (((size_t)(b * 64 + (t >> 5)) * 32 + d8) * 32 + (t & 31)) * 8;
    *(bf16x8*)(kt + kdst) = lo;
    *(bf16x8*)(kt + kdst + 4096) = hi;   // d8 + 16
  } else {
    // V transpose into blocked vtile, 64x64 tiles, XOR-8 swizzle in LDS
    int bid2 = bid - 1024;
    int b = bid2 >> 7, rem = bid2 & 127;
    int h0 = (rem >> 5) * 64, t0 = (rem & 31) * 64;
    int c4 = tid & 15, r0 = tid >> 4;
#pragma unroll
    for (int p = 0; p < 4; ++p) {
      int row = r0 + p * 16;
      const float4 f = *(const float4*)(v + ((size_t)(b * T_ + t0 + row)) * H_ + h0 + c4 * 4);
      ushort4 u;
      u.x = f2bf(f.x); u.y = f2bf(f.y); u.z = f2bf(f.z); u.w = f2bf(f.w);
      *(ushort4*)&tile[row][(c4 * 4) ^ (8 * ((row >> 3) & 7))] = u;
    }
    __syncthreads();
#pragma unroll
    for (int p = 0; p < 2; ++p) {
      int c = tid + p * 256;
      int h = c >> 3, tc = (c & 7) * 8;
      int xo = 8 * (c & 7);
      ushort4 u0, u1;
      u0.x = tile[tc + 0][h ^ xo]; u0.y = tile[tc + 1][h ^ xo];
      u0.z = tile[tc + 2][h ^ xo]; u0.w = tile[tc + 3][h ^ xo];
      u1.x = tile[tc + 4][h ^ xo]; u1.y = tile[tc + 5][h ^ xo];
      u1.z = tile[tc + 6][h ^ xo]; u1.w = tile[tc + 7][h ^ xo];
      int tg = t0 + tc;
      size_t dst = (((size_t)(b * 64 + (tg >> 5)) * 4 + ((tg >> 3) & 3)) * 256 + (h0 + h)) * 8;
      *(ushort4*)(vt + dst) = u0;
      *(ushort4*)(vt + dst + 4) = u1;
    }
  }
}

// ---- Flash attention on 32x32x16 MFMA: HALF the MFMA instruction count of
// the 16x16x32 versions at equal FLOPs (tests the 67cy/instr invariant).
// 512 thr, 8 waves x 32 q-rows (one 32-row MFMA tile each), q-tile 256,
// KVBLK=32, kv-split S=gridDim.z (4 -> grid (8,8,4)=256 blocks, 1/CU,
// 2 waves/SIMD). Per wave/iter: 16 QK + 16 PV + 2 rowsum = 34 MFMA,
// 34 ds_read_b128. Proven 2-barrier chain: acquire vmcnt(4), lgkm-only
// release, distance-2 prefetch, no setprio.
// Layouts (32x32x16): A row=l&31,k=(l>>5)*8+e; B col=l&31,k=(l>>5)*8+e;
// C/D col=l&31, row=(r&3)+8*(r>>2)+4*(l>>5).
__global__ __launch_bounds__(512, 2)
void attn_kernel(const float* __restrict__ q, const ushort* __restrict__ kt,
                 const ushort* __restrict__ vt, float* __restrict__ out,
                 float* __restrict__ opart, float* __restrict__ lpart) {
  __shared__ ushort Ksh[2][8192];       // [buf][d8][kv32][8]  32 KB
  __shared__ ushort Vsh[2][8192];       // [buf][kvq][h256][8] 32 KB
  __shared__ ushort Psh[8][32 * PSTR];  // per-wave P [32][32+8] 20 KB

  const int tid = threadIdx.x;
  const int w = tid >> 6, lane = tid & 63;
  const int l31 = lane & 31, lh = lane >> 5;
  const int b = blockIdx.x;             // linear%8==b -> XCD affinity
  const int q0 = blockIdx.y * 256;
  const int sp = blockIdx.z;
  const int S = gridDim.z;
  const int niter = (T_ / 32) / S;
  const int kvb = sp * (T_ / S);

  // ---- in-register RoPE of this wave's 32 Q rows into 16 A-frags ----
  // aq[ks]: Q[q0+w*32+l31][d = ks*16 + lh*8 + e], RoPE'd, bf16.
  bf16x8 aq[16];
  {
    const float* qb = q + ((size_t)(b * T_) + q0 + w * 32 + l31) * H_;
    const float tq = (float)(q0 + w * 32 + l31);
#pragma unroll
    for (int ks = 0; ks < 8; ++ks) {
      const float* pl = qb + ks * 16 + lh * 8;
      float4 x0 = *(const float4*)(pl);
      float4 x1 = *(const float4*)(pl + 4);
      float4 y0 = *(const float4*)(pl + 128);
      float4 y1 = *(const float4*)(pl + 132);
      float lo[8] = {x0.x, x0.y, x0.z, x0.w, x1.x, x1.y, x1.z, x1.w};
      float hi[8] = {y0.x, y0.y, y0.z, y0.w, y1.x, y1.y, y1.z, y1.w};
#pragma unroll
      for (int e = 0; e < 8; ++e) {
        int d = ks * 16 + lh * 8 + e;
        float rv = tq * exp2f((float)d * -0.103810252959f) * 0.15915494309f;
        float fr = rv - floorf(rv);
        float sn = __builtin_amdgcn_sinf(fr), cs = __builtin_amdgcn_cosf(fr);
        aq[ks][e]     = (short)f2bf(lo[e] * cs - hi[e] * sn);
        aq[ks + 8][e] = (short)f2bf(hi[e] * cs + lo[e] * sn);
      }
    }
  }

  f32x16 fz16;
#pragma unroll
  for (int i = 0; i < 16; ++i) fz16[i] = 0.f;
  f32x16 O[8], lac;
#pragma unroll
  for (int hb = 0; hb < 8; ++hb) O[hb] = fz16;
  lac = fz16;
  bf16x8 vones;
#pragma unroll
  for (int i = 0; i < 8; ++i) vones[i] = (short)0x3F80;

  // this split's stream: 64/S 16KB-subtiles starting at sp*(64/S)
  const ushort* ktb = kt + (size_t)(b * 64 + sp * (64 / S)) * 8192;
  const ushort* vtb = vt + (size_t)(b * 64 + sp * (64 / S)) * 8192;
  const int stoff = tid * 8;            // 16B/lane over 512 threads = 8KB/DMA

  // preload tiles 0,1 (per tile: 2 K-DMA + 2 V-DMA per thread)
#pragma unroll
  for (int tt = 0; tt < 2; ++tt) {
    const ushort* kg = ktb + (size_t)tt * 8192;
    const ushort* vg = vtb + (size_t)tt * 8192;
    gl_lds16(kg + stoff, &Ksh[tt][stoff]);
    gl_lds16(kg + stoff + 4096, &Ksh[tt][stoff + 4096]);
    gl_lds16(vg + stoff, &Vsh[tt][stoff]);
    gl_lds16(vg + stoff + 4096, &Vsh[tt][stoff + 4096]);
  }

  const float arb2 = SLOPE2 * (float)(q0 + w * 32);

  for (int it = 0; it < niter; ++it) {
    const int p = it & 1;
    // acquire: tile(it)'s 4 DMAs landed (issued 2 iters ago); tile(it+1)'s in flight
    __builtin_amdgcn_sched_barrier(0);
    if (it == niter - 1) __builtin_amdgcn_s_waitcnt(0x0070);   // vmcnt(0) lgkm(0)
    else                 __builtin_amdgcn_s_waitcnt(0x0F74);   // vmcnt(4)
    __builtin_amdgcn_s_barrier();
    __builtin_amdgcn_sched_barrier(0);

    // QK: 16 x mfma_32x32x16 over d=256 (k-slice ks of 16)
    f32x16 s = fz16;
#pragma unroll
    for (int ks = 0; ks < 16; ++ks) {
      bf16x8 kf = *(const bf16x8*)&Ksh[p][(((ks * 2 + lh) * 32) + l31) * 8];
      s = MFMA32(aq[ks], kf, s);
    }

    // softmax: p = exp2(s*SCALE2 + SLOPE2*(col-row)) -> wave-private Psh
    {
      float ac = SLOPE2 * (float)(kvb + it * 32 + l31) - arb2;
#pragma unroll
      for (int r = 0; r < 16; ++r) {
        int row = (r & 3) + 8 * (r >> 2) + 4 * lh;
        float pv = __builtin_amdgcn_exp2f(fmaf(s[r], SCALE2, ac - SLOPE2 * (float)row));
        Psh[w][row * PSTR + l31] = f2bf(pv);
      }
    }

    // PV + rowsum (lgkmcnt orders the wave-private P write->read)
    bf16x8 pf0 = *(const bf16x8*)&Psh[w][l31 * PSTR + lh * 8];
    bf16x8 pf1 = *(const bf16x8*)&Psh[w][l31 * PSTR + 16 + lh * 8];
    lac = MFMA32(pf0, vones, lac);
    lac = MFMA32(pf1, vones, lac);
#pragma unroll
    for (int hb = 0; hb < 8; ++hb) {
      bf16x8 vf0 = *(const bf16x8*)&Vsh[p][((lh * 256) + hb * 32 + l31) * 8];
      bf16x8 vf1 = *(const bf16x8*)&Vsh[p][(((2 + lh) * 256) + hb * 32 + l31) * 8];
      O[hb] = MFMA32(pf0, vf0, O[hb]);
      O[hb] = MFMA32(pf1, vf1, O[hb]);
    }

    // release: drain this wave's LDS ops, then barrier -> buf[p] free
    __builtin_amdgcn_sched_barrier(0);
    __builtin_amdgcn_s_waitcnt(0xC07F);   // lgkmcnt(0) only
    __builtin_amdgcn_s_barrier();
    __builtin_amdgcn_sched_barrier(0);

    // prefetch tile(it+2) into the buffer just freed
    if (it < niter - 2) {
      const ushort* kg = ktb + (size_t)(it + 2) * 8192;
      const ushort* vg = vtb + (size_t)(it + 2) * 8192;
      gl_lds16(kg + stoff, &Ksh[p][stoff]);
      gl_lds16(kg + stoff + 4096, &Ksh[p][stoff + 4096]);
      gl_lds16(vg + stoff, &Vsh[p][stoff]);
      gl_lds16(vg + stoff + 4096, &Vsh[p][stoff + 4096]);
    }
  }

  // epilogue: unnormalized O-partial + l-partial
  // C/D: col = hb*32 + l31 (h), row = (r&3)+8*(r>>2)+4*lh (q within 32)
  float* od = (sp == 0) ? out : (opart + (size_t)(sp - 1) * ELEMS);
  float* ob = od + ((size_t)(b * T_) + q0 + w * 32) * H_;
#pragma unroll
  for (int r = 0; r < 16; ++r) {
    int row = (r & 3) + 8 * (r >> 2) + 4 * lh;
#pragma unroll
    for (int hb = 0; hb < 8; ++hb)
      ob[(size_t)row * H_ + hb * 32 + l31] = O[hb][r];
  }
  if (l31 == 0) {
#pragma unroll
    for (int r = 0; r < 16; ++r) {
      int row = (r & 3) + 8 * (r >> 2) + 4 * lh;
      lpart[(size_t)(sp * B_ + b) * T_ + q0 + w * 32 + row] = lac[r];
    }
  }
}

// ---- combine: out = (O0 + ... + O_{S-1}) / (l0 + ... + l_{S-1}) ----
__global__ void combine_kernel(float* __restrict__ out, const float* __restrict__ opart,
                               const float* __restrict__ lpart, int S) {
  int idx = blockIdx.x * 256 + threadIdx.x;   // over B*T*H/4
  int row = idx >> 6;
  float l = lpart[row];
  for (int s = 1; s < S; ++s) l += lpart[(size_t)s * B_ * T_ + row];
  float inv = 1.0f / l;
  float4 a = ((const float4*)out)[idx];
  for (int s = 1; s < S; ++s) {
    float4 c = ((const float4*)opart)[(size_t)(s - 1) * (ELEMS / 4) + idx];
    a.x += c.x; a.y += c.y; a.z += c.z; a.w += c.w;
  }
  a.x *= inv; a.y *= inv; a.z *= inv; a.w *= inv;
  ((float4*)out)[idx] = a;
}

extern "C" void kernel_launch(void* const* d_in, const int* in_sizes, int n_in,
                              void* d_out, int out_size, void* d_ws, size_t ws_size,
                              hipStream_t stream) {
  const float* q = (const float*)d_in[0];
  const float* k = (const float*)d_in[1];
  const float* v = (const float*)d_in[2];
  float* out = (float*)d_out;

  ushort* kt = (ushort*)d_ws;
  ushort* vt = kt + ELEMS;
  float* opart = (float*)(vt + ELEMS);
  // S=4 needs: kt+vt (2*ELEMS*2B) + 3 opart (3*ELEMS*4B) + lpart (4*B*T*4B)
  const size_t need4 = ELEMS * 4 + 3 * ELEMS * 4 + (size_t)4 * B_ * T_ * 4;
  const int S = (ws_size >= need4) ? 4 : 2;
  float* lpart = opart + (size_t)(S - 1) * ELEMS;

  prep_kernel<<<dim3(2048), 256, 0, stream>>>(k, v, kt, vt);
  attn_kernel<<<dim3(B_, T_ / 256, S), 512, 0, stream>>>(q, kt, vt, out, opart, lpart);
  combine_kernel<<<dim3((B_ * T_ * H_ / 4) / 256), 256, 0, stream>>>(out, opart, lpart, S);
}